// Round 1
// baseline (1312.749 us; speedup 1.0000x reference)
//
#include <hip/hip_runtime.h>
#include <math.h>

#define FIN 256
#define HID 128
#define NCLS 40

// ---------------- small utility kernels ----------------

__global__ void k_init_deg(float* deg, int n) {
    int i = blockIdx.x * blockDim.x + threadIdx.x;
    if (i < n) deg[i] = 1.0f;  // self-loop contributes 1 to in-degree
}

__global__ void k_count_deg(const int* __restrict__ dst, int E, float* deg) {
    int e = blockIdx.x * blockDim.x + threadIdx.x;
    if (e < E) atomicAdd(&deg[dst[e]], 1.0f);
}

__global__ void k_dinv(float* deg, int n) {
    int i = blockIdx.x * blockDim.x + threadIdx.x;
    if (i < n) deg[i] = rsqrtf(deg[i]);  // deg >= 1 always (self-loops)
}

__global__ void k_zero(float* p, size_t n) {
    size_t i = (size_t)blockIdx.x * blockDim.x + threadIdx.x;
    if (i < n) p[i] = 0.0f;
}

__global__ void k_relu_bias(float* __restrict__ A, const float* __restrict__ b, int total) {
    int i = blockIdx.x * blockDim.x + threadIdx.x;
    if (i < total) {
        A[i] = fmaxf(A[i] + b[i & (HID - 1)], 0.0f);
    }
}

__global__ void k_init_out(float* __restrict__ out, const float* __restrict__ b2, int total) {
    int i = blockIdx.x * blockDim.x + threadIdx.x;
    if (i < total) out[i] = b2[i % NCLS];
}

// ---------------- GEMM1: H = X @ W1  (M x 256) @ (256 x 128) ----------------

__global__ __launch_bounds__(256) void k_gemm1(const float* __restrict__ X,
                                               const float* __restrict__ W,
                                               float* __restrict__ Hout, int M) {
    const int K = FIN, N = HID;
    __shared__ float As[8][128 + 4];
    __shared__ float Bs[8][128 + 4];
    int bm = blockIdx.x * 128;
    int tid = threadIdx.x;
    int tx = tid & 15, ty = tid >> 4;
    float acc[8][8];
#pragma unroll
    for (int i = 0; i < 8; i++)
#pragma unroll
        for (int j = 0; j < 8; j++) acc[i][j] = 0.0f;

    for (int kt = 0; kt < K; kt += 8) {
        // A tile: 128 rows x 8 k -> 256 float4 loads (row = tid/2, kq = (tid&1)*4)
        {
            int row = tid >> 1;
            int kq = (tid & 1) * 4;
            int gr = bm + row;
            float4 v = make_float4(0.f, 0.f, 0.f, 0.f);
            if (gr < M) v = *reinterpret_cast<const float4*>(&X[(size_t)gr * K + kt + kq]);
            As[kq + 0][row] = v.x;
            As[kq + 1][row] = v.y;
            As[kq + 2][row] = v.z;
            As[kq + 3][row] = v.w;
        }
        // B tile: 8 k x 128 n -> 256 float4 loads (k = tid/32, n4 = (tid&31)*4)
        {
            int k = tid >> 5;
            int n4 = (tid & 31) * 4;
            float4 v = *reinterpret_cast<const float4*>(&W[(size_t)(kt + k) * N + n4]);
            *reinterpret_cast<float4*>(&Bs[k][n4]) = v;
        }
        __syncthreads();
#pragma unroll
        for (int k = 0; k < 8; k++) {
            float a[8], b[8];
#pragma unroll
            for (int i = 0; i < 8; i++) a[i] = As[k][ty * 8 + i];
#pragma unroll
            for (int j = 0; j < 8; j++) b[j] = Bs[k][tx * 8 + j];
#pragma unroll
            for (int i = 0; i < 8; i++)
#pragma unroll
                for (int j = 0; j < 8; j++) acc[i][j] = fmaf(a[i], b[j], acc[i][j]);
        }
        __syncthreads();
    }
#pragma unroll
    for (int i = 0; i < 8; i++) {
        int gr = bm + ty * 8 + i;
        if (gr < M) {
#pragma unroll
            for (int j = 0; j < 8; j++) Hout[(size_t)gr * N + tx * 8 + j] = acc[i][j];
        }
    }
}

// ---------------- edge aggregation, layer 1 (128 feats, one wave/edge) ----------------

__global__ __launch_bounds__(256) void k_agg1(const float* __restrict__ Hsrc,
                                              const int* __restrict__ src,
                                              const int* __restrict__ dst,
                                              const float* __restrict__ dinv,
                                              float* __restrict__ Out, int E, int n) {
    int wave = blockIdx.x * 4 + (threadIdx.x >> 6);
    int lane = threadIdx.x & 63;
    int Etot = E + n;
    if (wave >= Etot) return;
    int s, d;
    if (wave < E) {
        s = src[wave];
        d = dst[wave];
    } else {
        s = d = wave - E;  // self-loop
    }
    float w = dinv[s] * dinv[d];
    const float* hr = &Hsrc[(size_t)s * HID];
    float* orow = &Out[(size_t)d * HID];
    atomicAdd(&orow[lane], hr[lane] * w);
    atomicAdd(&orow[lane + 64], hr[lane + 64] * w);
}

// ---------------- GEMM2: Z = H2 @ W2  (M x 128) @ (128 x 40) ----------------

__global__ __launch_bounds__(256) void k_gemm2(const float* __restrict__ H2,
                                               const float* __restrict__ W2,
                                               float* __restrict__ Z, int M) {
    __shared__ float Ws[HID * NCLS];       // 20 KB, [k][c]
    __shared__ float Hs[64][HID + 1];      // 33 KB
    int tid = threadIdx.x;
    for (int l = tid; l < HID * NCLS; l += 256) Ws[l] = W2[l];
    int bm = blockIdx.x * 64;
#pragma unroll
    for (int i = 0; i < 8; i++) {
        int pos = tid + i * 256;       // 2048 float4 slots: 64 rows x 32
        int row = pos >> 5;
        int q = (pos & 31) << 2;
        int gr = bm + row;
        float4 v = make_float4(0.f, 0.f, 0.f, 0.f);
        if (gr < M) v = *reinterpret_cast<const float4*>(&H2[(size_t)gr * HID + q]);
        *reinterpret_cast<float4*>(&Hs[row][q]) = v;
    }
    __syncthreads();
#pragma unroll
    for (int i = 0; i < 10; i++) {
        int o = tid + i * 256;  // < 2560 = 64 rows * 40 cols
        int r = o / NCLS;
        int c = o - r * NCLS;
        float acc = 0.0f;
#pragma unroll 8
        for (int k = 0; k < HID; k++) acc = fmaf(Hs[r][k], Ws[k * NCLS + c], acc);
        int gr = bm + r;
        if (gr < M) Z[(size_t)gr * NCLS + c] = acc;
    }
}

// ---------------- edge aggregation, layer 2 (40 feats) ----------------

__global__ __launch_bounds__(256) void k_agg2(const float* __restrict__ Z,
                                              const int* __restrict__ src,
                                              const int* __restrict__ dst,
                                              const float* __restrict__ dinv,
                                              float* __restrict__ Out, int E, int n) {
    int wave = blockIdx.x * 4 + (threadIdx.x >> 6);
    int lane = threadIdx.x & 63;
    int Etot = E + n;
    if (wave >= Etot) return;
    int s, d;
    if (wave < E) {
        s = src[wave];
        d = dst[wave];
    } else {
        s = d = wave - E;
    }
    float w = dinv[s] * dinv[d];
    if (lane < NCLS) atomicAdd(&Out[(size_t)d * NCLS + lane], Z[(size_t)s * NCLS + lane] * w);
}

// ---------------- log_softmax in place, one wave per row ----------------

__global__ __launch_bounds__(256) void k_logsoftmax(float* __restrict__ Out, int n) {
    int row = blockIdx.x * 4 + (threadIdx.x >> 6);
    int lane = threadIdx.x & 63;
    if (row >= n) return;
    float v = (lane < NCLS) ? Out[(size_t)row * NCLS + lane] : -INFINITY;
    float m = v;
#pragma unroll
    for (int off = 32; off; off >>= 1) m = fmaxf(m, __shfl_xor(m, off));
    float e = (lane < NCLS) ? __expf(v - m) : 0.0f;
    float ssum = e;
#pragma unroll
    for (int off = 32; off; off >>= 1) ssum += __shfl_xor(ssum, off);
    float lse = m + logf(ssum);
    if (lane < NCLS) Out[(size_t)row * NCLS + lane] = v - lse;
}

// ---------------- launch ----------------

extern "C" void kernel_launch(void* const* d_in, const int* in_sizes, int n_in,
                              void* d_out, int out_size, void* d_ws, size_t ws_size,
                              hipStream_t stream) {
    const float* x  = (const float*)d_in[0];
    const int* ei   = (const int*)d_in[1];
    const float* W1 = (const float*)d_in[2];
    const float* b1 = (const float*)d_in[3];
    const float* W2 = (const float*)d_in[4];
    const float* b2 = (const float*)d_in[5];
    float* out = (float*)d_out;

    const int n = in_sizes[0] / FIN;       // 100000
    const int E = in_sizes[1] / 2;         // 1600000
    const int* src = ei;
    const int* dst = ei + E;

    float* ws = (float*)d_ws;
    float* dinv = ws;                          // n floats
    float* h    = ws + 131072;                 // n*128 floats (later reused for Z)
    float* agg1 = h + (size_t)n * HID;         // n*128 floats (becomes H2 after relu)
    float* z    = h;                           // reuse (h dead after agg1)

    const int Etot = E + n;
    const int eb = (Etot + 3) / 4;  // wave-per-edge blocks (4 waves / 256-thr block)

    // degree + dinv
    k_init_deg<<<(n + 255) / 256, 256, 0, stream>>>(dinv, n);
    k_count_deg<<<(E + 255) / 256, 256, 0, stream>>>(dst, E, dinv);
    k_dinv<<<(n + 255) / 256, 256, 0, stream>>>(dinv, n);

    // layer 1
    k_gemm1<<<(n + 127) / 128, 256, 0, stream>>>(x, W1, h, n);
    k_zero<<<(int)(((size_t)n * HID + 1023) / 1024), 1024, 0, stream>>>(agg1, (size_t)n * HID);
    k_agg1<<<eb, 256, 0, stream>>>(h, src, dst, dinv, agg1, E, n);
    k_relu_bias<<<(n * HID + 255) / 256, 256, 0, stream>>>(agg1, b1, n * HID);

    // layer 2
    k_gemm2<<<(n + 63) / 64, 256, 0, stream>>>(agg1, W2, z, n);
    k_init_out<<<(n * NCLS + 255) / 256, 256, 0, stream>>>(out, b2, n * NCLS);
    k_agg2<<<eb, 256, 0, stream>>>(z, src, dst, dinv, out, E, n);

    // log_softmax
    k_logsoftmax<<<(n + 3) / 4, 256, 0, stream>>>(out, n);
}

// Round 2
// 631.879 us; speedup vs baseline: 2.0775x; 2.0775x over previous
//
#include <hip/hip_runtime.h>
#include <math.h>

#define FIN 256
#define HID 128
#define NCLS 40

// ---------------- CSR build ----------------

__global__ void k_zero_int(int* p, int n) {
    int i = blockIdx.x * blockDim.x + threadIdx.x;
    if (i < n) p[i] = 0;
}

__global__ void k_hist(const int* __restrict__ dst, int E, int* __restrict__ cnt) {
    int e = blockIdx.x * blockDim.x + threadIdx.x;
    if (e < E) atomicAdd(&cnt[dst[e]], 1);
}

// per-block inclusive scan (1024 elems/block) -> off (inclusive), bsum[b] = block total
__global__ __launch_bounds__(1024) void k_scan1(const int* __restrict__ cnt, int* __restrict__ off,
                                                int* __restrict__ bsum, int n) {
    __shared__ int sm[1024];
    int t = threadIdx.x;
    int i = blockIdx.x * 1024 + t;
    int v = (i < n) ? cnt[i] : 0;
    sm[t] = v;
    __syncthreads();
    for (int o = 1; o < 1024; o <<= 1) {
        int u = (t >= o) ? sm[t - o] : 0;
        __syncthreads();
        sm[t] += u;
        __syncthreads();
    }
    if (i < n) off[i] = sm[t];
    if (t == 1023) bsum[blockIdx.x] = sm[1023];
}

// single-wave exclusive scan of block sums (nb <= 128)
__global__ void k_scan2(int* __restrict__ bsum, int nb) {
    int lane = threadIdx.x;
    int v0 = (lane < nb) ? bsum[lane] : 0;
    int v1 = (64 + lane < nb) ? bsum[64 + lane] : 0;
    int o0 = v0, o1 = v1;
    for (int o = 1; o < 64; o <<= 1) {
        int t = __shfl_up(v0, o);
        if (lane >= o) v0 += t;
    }
    int tot0 = __shfl(v0, 63);
    for (int o = 1; o < 64; o <<= 1) {
        int t = __shfl_up(v1, o);
        if (lane >= o) v1 += t;
    }
    v1 += tot0;
    if (lane < nb) bsum[lane] = v0 - o0;
    if (64 + lane < nb) bsum[64 + lane] = v1 - o1;
}

// finalize: off -> exclusive, cursor = off, dinv = rsqrt(deg+1)
__global__ void k_scan3(int* __restrict__ off, const int* __restrict__ cnt,
                        const int* __restrict__ bsum, int* __restrict__ cursor,
                        float* __restrict__ dinv, int n) {
    int i = blockIdx.x * blockDim.x + threadIdx.x;
    if (i < n) {
        int excl = off[i] - cnt[i] + bsum[i >> 10];
        off[i] = excl;
        cursor[i] = excl;
        dinv[i] = rsqrtf((float)(cnt[i] + 1));
    }
}

__global__ void k_scatter(const int* __restrict__ src, const int* __restrict__ dst, int E,
                          int* __restrict__ cursor, int* __restrict__ eidx) {
    int e = blockIdx.x * blockDim.x + threadIdx.x;
    if (e < E) {
        int d = dst[e];
        int pos = atomicAdd(&cursor[d], 1);
        eidx[pos] = src[e];
    }
}

// ---------------- GEMM1: H = X @ W1  (M x 256) @ (256 x 128) ----------------

__global__ __launch_bounds__(256) void k_gemm1(const float* __restrict__ X,
                                               const float* __restrict__ W,
                                               float* __restrict__ Hout, int M) {
    const int K = FIN, N = HID;
    __shared__ float As[8][128 + 4];
    __shared__ float Bs[8][128 + 4];
    int bm = blockIdx.x * 128;
    int tid = threadIdx.x;
    int tx = tid & 15, ty = tid >> 4;
    float acc[8][8];
#pragma unroll
    for (int i = 0; i < 8; i++)
#pragma unroll
        for (int j = 0; j < 8; j++) acc[i][j] = 0.0f;

    for (int kt = 0; kt < K; kt += 8) {
        {
            int row = tid >> 1;
            int kq = (tid & 1) * 4;
            int gr = bm + row;
            float4 v = make_float4(0.f, 0.f, 0.f, 0.f);
            if (gr < M) v = *reinterpret_cast<const float4*>(&X[(size_t)gr * K + kt + kq]);
            As[kq + 0][row] = v.x;
            As[kq + 1][row] = v.y;
            As[kq + 2][row] = v.z;
            As[kq + 3][row] = v.w;
        }
        {
            int k = tid >> 5;
            int n4 = (tid & 31) * 4;
            float4 v = *reinterpret_cast<const float4*>(&W[(size_t)(kt + k) * N + n4]);
            *reinterpret_cast<float4*>(&Bs[k][n4]) = v;
        }
        __syncthreads();
#pragma unroll
        for (int k = 0; k < 8; k++) {
            float a[8], b[8];
#pragma unroll
            for (int i = 0; i < 8; i++) a[i] = As[k][ty * 8 + i];
#pragma unroll
            for (int j = 0; j < 8; j++) b[j] = Bs[k][tx * 8 + j];
#pragma unroll
            for (int i = 0; i < 8; i++)
#pragma unroll
                for (int j = 0; j < 8; j++) acc[i][j] = fmaf(a[i], b[j], acc[i][j]);
        }
        __syncthreads();
    }
#pragma unroll
    for (int i = 0; i < 8; i++) {
        int gr = bm + ty * 8 + i;
        if (gr < M) {
#pragma unroll
            for (int j = 0; j < 8; j++) Hout[(size_t)gr * N + tx * 8 + j] = acc[i][j];
        }
    }
}

// ---------------- agg1 (gather): H2[d] = relu(b1 + sum_{s in N(d)} w*H[s]) ----------------

__global__ __launch_bounds__(256) void k_agg1_gather(const float* __restrict__ H,
                                                     const int* __restrict__ eidx,
                                                     const int* __restrict__ off,
                                                     const int* __restrict__ cnt,
                                                     const float* __restrict__ dinv,
                                                     const float* __restrict__ b1,
                                                     float* __restrict__ H2, int n) {
    int node = blockIdx.x * 4 + (threadIdx.x >> 6);
    int lane = threadIdx.x & 63;
    if (node >= n) return;
    float di = dinv[node];
    const float* hn = &H[(size_t)node * HID];
    float a0 = hn[lane] * di * di;          // self-loop
    float a1 = hn[lane + 64] * di * di;
    int start = off[node], deg = cnt[node];
    for (int base = 0; base < deg; base += 64) {
        int kk = min(64, deg - base);
        int s = 0;
        float w = 0.0f;
        if (lane < kk) {
            s = eidx[start + base + lane];
            w = dinv[s] * di;
        }
        for (int j = 0; j < kk; j++) {
            int sj = __shfl(s, j);
            float wj = __shfl(w, j);
            const float* hs = &H[(size_t)sj * HID];
            a0 = fmaf(hs[lane], wj, a0);
            a1 = fmaf(hs[lane + 64], wj, a1);
        }
    }
    a0 = fmaxf(a0 + b1[lane], 0.0f);
    a1 = fmaxf(a1 + b1[lane + 64], 0.0f);
    float* o = &H2[(size_t)node * HID];
    o[lane] = a0;
    o[lane + 64] = a1;
}

// ---------------- GEMM2: Z = H2 @ W2  (M x 128) @ (128 x 40) ----------------

__global__ __launch_bounds__(256) void k_gemm2(const float* __restrict__ H2,
                                               const float* __restrict__ W2,
                                               float* __restrict__ Z, int M) {
    __shared__ float Ws[HID * NCLS];
    __shared__ float Hs[64][HID + 1];
    int tid = threadIdx.x;
    for (int l = tid; l < HID * NCLS; l += 256) Ws[l] = W2[l];
    int bm = blockIdx.x * 64;
#pragma unroll
    for (int i = 0; i < 8; i++) {
        int pos = tid + i * 256;
        int row = pos >> 5;
        int q = (pos & 31) << 2;
        int gr = bm + row;
        float4 v = make_float4(0.f, 0.f, 0.f, 0.f);
        if (gr < M) v = *reinterpret_cast<const float4*>(&H2[(size_t)gr * HID + q]);
        *reinterpret_cast<float4*>(&Hs[row][q]) = v;
    }
    __syncthreads();
#pragma unroll
    for (int i = 0; i < 10; i++) {
        int o = tid + i * 256;
        int r = o / NCLS;
        int c = o - r * NCLS;
        float acc = 0.0f;
#pragma unroll 8
        for (int k = 0; k < HID; k++) acc = fmaf(Hs[r][k], Ws[k * NCLS + c], acc);
        int gr = bm + r;
        if (gr < M) Z[(size_t)gr * NCLS + c] = acc;
    }
}

// ---------------- agg2 (gather) + bias + log_softmax fused ----------------

__global__ __launch_bounds__(256) void k_agg2_lsm(const float* __restrict__ Z,
                                                  const int* __restrict__ eidx,
                                                  const int* __restrict__ off,
                                                  const int* __restrict__ cnt,
                                                  const float* __restrict__ dinv,
                                                  const float* __restrict__ b2,
                                                  float* __restrict__ Out, int n) {
    int node = blockIdx.x * 4 + (threadIdx.x >> 6);
    int lane = threadIdx.x & 63;
    if (node >= n) return;
    float di = dinv[node];
    float a = (lane < NCLS) ? Z[(size_t)node * NCLS + lane] * di * di : 0.0f;
    int start = off[node], deg = cnt[node];
    for (int base = 0; base < deg; base += 64) {
        int kk = min(64, deg - base);
        int s = 0;
        float w = 0.0f;
        if (lane < kk) {
            s = eidx[start + base + lane];
            w = dinv[s] * di;
        }
        for (int j = 0; j < kk; j++) {
            int sj = __shfl(s, j);
            float wj = __shfl(w, j);
            if (lane < NCLS) a = fmaf(Z[(size_t)sj * NCLS + lane], wj, a);
        }
    }
    float v = (lane < NCLS) ? a + b2[lane] : -INFINITY;
    float m = v;
#pragma unroll
    for (int o = 32; o; o >>= 1) m = fmaxf(m, __shfl_xor(m, o));
    float e = (lane < NCLS) ? __expf(v - m) : 0.0f;
    float ssum = e;
#pragma unroll
    for (int o = 32; o; o >>= 1) ssum += __shfl_xor(ssum, o);
    float lse = m + logf(ssum);
    if (lane < NCLS) Out[(size_t)node * NCLS + lane] = v - lse;
}

// ---------------- launch ----------------

extern "C" void kernel_launch(void* const* d_in, const int* in_sizes, int n_in,
                              void* d_out, int out_size, void* d_ws, size_t ws_size,
                              hipStream_t stream) {
    const float* x  = (const float*)d_in[0];
    const int* ei   = (const int*)d_in[1];
    const float* W1 = (const float*)d_in[2];
    const float* b1 = (const float*)d_in[3];
    const float* W2 = (const float*)d_in[4];
    const float* b2 = (const float*)d_in[5];
    float* out = (float*)d_out;

    const int n = in_sizes[0] / FIN;       // 100000
    const int E = in_sizes[1] / 2;         // 1600000
    const int* src = ei;
    const int* dst = ei + E;

    // workspace layout
    int* cnt    = (int*)d_ws;                  // n
    int* off    = cnt + n;                     // n
    int* cursor = off + n;                     // n
    int* bsum   = cursor + n;                  // 128
    float* dinv = (float*)(bsum + 128);        // n
    int* eidx   = (int*)(dinv + n);            // E
    size_t hoff = ((size_t)(5 * n + 128) + (size_t)E + 3) & ~(size_t)3;  // align 16B
    float* h    = (float*)d_ws + hoff;         // n*128
    float* h2   = h + (size_t)n * HID;         // n*128
    float* z    = h;                           // reuse (h dead after agg1)

    const int nb = (n + 1023) / 1024;

    // CSR build + dinv
    k_zero_int<<<(n + 255) / 256, 256, 0, stream>>>(cnt, n);
    k_hist<<<(E + 255) / 256, 256, 0, stream>>>(dst, E, cnt);
    k_scan1<<<nb, 1024, 0, stream>>>(cnt, off, bsum, n);
    k_scan2<<<1, 64, 0, stream>>>(bsum, nb);
    k_scan3<<<(n + 255) / 256, 256, 0, stream>>>(off, cnt, bsum, cursor, dinv, n);
    k_scatter<<<(E + 255) / 256, 256, 0, stream>>>(src, dst, E, cursor, eidx);

    // layer 1
    k_gemm1<<<(n + 127) / 128, 256, 0, stream>>>(x, W1, h, n);
    k_agg1_gather<<<(n + 3) / 4, 256, 0, stream>>>(h, eidx, off, cnt, dinv, b1, h2, n);

    // layer 2 (+ fused bias + log_softmax)
    k_gemm2<<<(n + 63) / 64, 256, 0, stream>>>(h2, W2, z, n);
    k_agg2_lsm<<<(n + 3) / 4, 256, 0, stream>>>(z, eidx, off, cnt, dinv, b2, out, n);
}

// Round 3
// 470.687 us; speedup vs baseline: 2.7890x; 1.3425x over previous
//
#include <hip/hip_runtime.h>
#include <hip/hip_fp16.h>
#include <math.h>

#define FIN 256
#define HID 128
#define NCLS 40
#define ZP 64

typedef __attribute__((ext_vector_type(8))) short short8_t;
typedef __attribute__((ext_vector_type(4))) float f32x4;

static __device__ __forceinline__ ushort f2bf(float f) {
    unsigned u = __float_as_uint(f);
    u += 0x7FFF + ((u >> 16) & 1);
    return (ushort)(u >> 16);
}

// ---------------- CSR build ----------------

__global__ void k_zero_int(int* p, int n) {
    int i = blockIdx.x * blockDim.x + threadIdx.x;
    if (i < n) p[i] = 0;
}

__global__ void k_hist(const int* __restrict__ dst, int E, int* __restrict__ cnt) {
    int e = blockIdx.x * blockDim.x + threadIdx.x;
    if (e < E) atomicAdd(&cnt[dst[e]], 1);
}

__global__ __launch_bounds__(1024) void k_scan1(const int* __restrict__ cnt, int* __restrict__ off,
                                                int* __restrict__ bsum, int n) {
    __shared__ int sm[1024];
    int t = threadIdx.x;
    int i = blockIdx.x * 1024 + t;
    int v = (i < n) ? cnt[i] : 0;
    sm[t] = v;
    __syncthreads();
    for (int o = 1; o < 1024; o <<= 1) {
        int u = (t >= o) ? sm[t - o] : 0;
        __syncthreads();
        sm[t] += u;
        __syncthreads();
    }
    if (i < n) off[i] = sm[t];
    if (t == 1023) bsum[blockIdx.x] = sm[1023];
}

__global__ void k_scan2(int* __restrict__ bsum, int nb) {
    int lane = threadIdx.x;
    int v0 = (lane < nb) ? bsum[lane] : 0;
    int v1 = (64 + lane < nb) ? bsum[64 + lane] : 0;
    int o0 = v0, o1 = v1;
    for (int o = 1; o < 64; o <<= 1) {
        int t = __shfl_up(v0, o);
        if (lane >= o) v0 += t;
    }
    int tot0 = __shfl(v0, 63);
    for (int o = 1; o < 64; o <<= 1) {
        int t = __shfl_up(v1, o);
        if (lane >= o) v1 += t;
    }
    v1 += tot0;
    if (lane < nb) bsum[lane] = v0 - o0;
    if (64 + lane < nb) bsum[64 + lane] = v1 - o1;
}

__global__ void k_scan3(int* __restrict__ off, const int* __restrict__ cnt,
                        const int* __restrict__ bsum, int* __restrict__ cursor,
                        float* __restrict__ dinv, int n) {
    int i = blockIdx.x * blockDim.x + threadIdx.x;
    if (i < n) {
        int excl = off[i] - cnt[i] + bsum[i >> 10];
        off[i] = excl;
        cursor[i] = excl;
        dinv[i] = rsqrtf((float)(cnt[i] + 1));
    }
}

// scatter src + precomputed edge weight, packed int2 {src, bits(w)}
__global__ void k_scatter(const int* __restrict__ src, const int* __restrict__ dst, int E,
                          int* __restrict__ cursor, const float* __restrict__ dinv,
                          int2* __restrict__ eew) {
    int e = blockIdx.x * blockDim.x + threadIdx.x;
    if (e < E) {
        int d = dst[e], s = src[e];
        int pos = atomicAdd(&cursor[d], 1);
        eew[pos] = make_int2(s, __float_as_int(dinv[s] * dinv[d]));
    }
}

// ---------------- W1 -> bf16 transposed [col][k] ----------------

__global__ void k_w1_cvt(const float* __restrict__ W1, ushort* __restrict__ Wt) {
    int idx = blockIdx.x * 256 + threadIdx.x;  // 128*256
    int c = idx >> 8, k = idx & 255;
    Wt[idx] = f2bf(W1[(size_t)k * HID + c]);
}

// ---------------- GEMM1 (MFMA bf16): H16 = fp16(X @ W1) ----------------
// block = 256 thr (4 waves), 64 rows x 128 cols per block

__global__ __launch_bounds__(256) void k_gemm1(const float* __restrict__ X,
                                               const ushort* __restrict__ Wt,
                                               __half* __restrict__ H16, int M) {
    __shared__ uint4 wlds[128 * 32];  // 64 KB, chunk-swizzled [col][32 chunks of 8 bf16]
    int tid = threadIdx.x;
    const uint4* wg = (const uint4*)Wt;
#pragma unroll
    for (int i = 0; i < 16; i++) {
        int e = tid + i * 256;
        int r = e >> 5, ch = e & 31;
        wlds[r * 32 + (ch ^ (r & 7))] = wg[e];
    }
    __syncthreads();

    int wid = tid >> 6, lane = tid & 63;
    int q = lane & 15, kg = lane >> 4;
    int row = blockIdx.x * 64 + wid * 16 + q;
    int lrow = min(row, M - 1);
    const float* xr = X + (size_t)lrow * FIN;

    f32x4 acc[8];
#pragma unroll
    for (int c = 0; c < 8; c++) acc[c] = (f32x4){0.f, 0.f, 0.f, 0.f};

#pragma unroll
    for (int kt = 0; kt < 8; kt++) {
        int k0 = kt * 32 + kg * 8;
        float4 f0 = *(const float4*)(xr + k0);
        float4 f1 = *(const float4*)(xr + k0 + 4);
        short8_t a;
        a[0] = (short)f2bf(f0.x); a[1] = (short)f2bf(f0.y);
        a[2] = (short)f2bf(f0.z); a[3] = (short)f2bf(f0.w);
        a[4] = (short)f2bf(f1.x); a[5] = (short)f2bf(f1.y);
        a[6] = (short)f2bf(f1.z); a[7] = (short)f2bf(f1.w);
        int ch = kt * 4 + kg;
#pragma unroll
        for (int c = 0; c < 8; c++) {
            int col = c * 16 + q;
            short8_t b = *(const short8_t*)&wlds[col * 32 + (ch ^ (col & 7))];
            acc[c] = __builtin_amdgcn_mfma_f32_16x16x32_bf16(a, b, acc[c], 0, 0, 0);
        }
    }

    int r0 = blockIdx.x * 64 + wid * 16 + kg * 4;  // C/D: row=(lane>>4)*4+i, col=lane&15
#pragma unroll
    for (int c = 0; c < 8; c++) {
        int col = c * 16 + q;
#pragma unroll
        for (int i = 0; i < 4; i++) {
            int r = r0 + i;
            if (r < M) H16[(size_t)r * HID + col] = __float2half(acc[c][i]);
        }
    }
}

// ---------------- agg1: H2 = fp16(relu(b1 + sum w*H16[s])) ----------------
// one wave per node; 4 groups of 16 lanes, 4 edges in flight

__global__ __launch_bounds__(256) void k_agg1(const __half* __restrict__ H16,
                                              const int2* __restrict__ eew,
                                              const int* __restrict__ off,
                                              const int* __restrict__ cnt,
                                              const float* __restrict__ dinv,
                                              const float* __restrict__ b1,
                                              __half* __restrict__ H2, int n) {
    int node = blockIdx.x * 4 + (threadIdx.x >> 6);
    int lane = threadIdx.x & 63;
    if (node >= n) return;
    int q = lane & 15, g = lane >> 4;
    float di = dinv[node];
    int start = off[node], total = cnt[node] + 1;  // virtual edge 0 = self-loop

    float acc[8] = {0.f, 0.f, 0.f, 0.f, 0.f, 0.f, 0.f, 0.f};

    for (int base = 0; base < total; base += 4) {
        int sm = 0;
        float wm = 0.f;
        if (lane < 4) {
            int vj = base + lane;
            if (vj == 0) {
                sm = node; wm = di * di;
            } else if (vj < total) {
                int2 t = eew[start + vj - 1];
                sm = t.x; wm = __int_as_float(t.y);
            }
        }
        int s = __shfl(sm, g);
        float w = __shfl(wm, g);
        const uint4* rp = (const uint4*)(H16 + (size_t)s * HID);
        uint4 v = rp[q];
        float2 f;
        f = __half22float2(*(const __half2*)&v.x);
        acc[0] = fmaf(f.x, w, acc[0]); acc[1] = fmaf(f.y, w, acc[1]);
        f = __half22float2(*(const __half2*)&v.y);
        acc[2] = fmaf(f.x, w, acc[2]); acc[3] = fmaf(f.y, w, acc[3]);
        f = __half22float2(*(const __half2*)&v.z);
        acc[4] = fmaf(f.x, w, acc[4]); acc[5] = fmaf(f.y, w, acc[5]);
        f = __half22float2(*(const __half2*)&v.w);
        acc[6] = fmaf(f.x, w, acc[6]); acc[7] = fmaf(f.y, w, acc[7]);
    }

#pragma unroll
    for (int o = 16; o <= 32; o <<= 1)
#pragma unroll
        for (int i = 0; i < 8; i++) acc[i] += __shfl_xor(acc[i], o);

    if (lane < 16) {
        float r[8];
#pragma unroll
        for (int i = 0; i < 8; i++) r[i] = fmaxf(acc[i] + b1[q * 8 + i], 0.f);
        __half2 p0 = __floats2half2_rn(r[0], r[1]);
        __half2 p1 = __floats2half2_rn(r[2], r[3]);
        __half2 p2 = __floats2half2_rn(r[4], r[5]);
        __half2 p3 = __floats2half2_rn(r[6], r[7]);
        uint4 o4;
        o4.x = *(unsigned*)&p0; o4.y = *(unsigned*)&p1;
        o4.z = *(unsigned*)&p2; o4.w = *(unsigned*)&p3;
        *(uint4*)(H2 + (size_t)node * HID + q * 8) = o4;
    }
}

// ---------------- GEMM2: Zp = fp16(H2 @ W2), padded to 64 cols ----------------

__global__ __launch_bounds__(256) void k_gemm2(const __half* __restrict__ H2,
                                               const float* __restrict__ W2,
                                               __half* __restrict__ Zp, int M) {
    __shared__ float Ws[HID * NCLS];   // [k][c]
    __shared__ float Hs[64][HID + 1];
    int tid = threadIdx.x;
    for (int l = tid; l < HID * NCLS; l += 256) Ws[l] = W2[l];
    int bm = blockIdx.x * 64;
#pragma unroll
    for (int i = 0; i < 16; i++) {
        int o = tid + i * 256;  // 64 rows x 64 half2
        int r = o >> 6, p = o & 63;
        int gr = bm + r;
        float2 f = make_float2(0.f, 0.f);
        if (gr < M) f = __half22float2(*(const __half2*)(H2 + (size_t)gr * HID + p * 2));
        Hs[r][p * 2] = f.x;
        Hs[r][p * 2 + 1] = f.y;
    }
    __syncthreads();
#pragma unroll
    for (int i = 0; i < 16; i++) {
        int o = tid + i * 256;  // 64 rows x 64 cols
        int r = o >> 6, c = o & 63;
        int gr = bm + r;
        if (gr >= M) continue;
        float a = 0.f;
        if (c < NCLS) {
#pragma unroll 8
            for (int k = 0; k < HID; k++) a = fmaf(Hs[r][k], Ws[k * NCLS + c], a);
        }
        Zp[(size_t)gr * ZP + c] = __float2half(a);
    }
}

// ---------------- agg2 + bias + log_softmax ----------------
// one wave per node; 8 groups of 8 lanes, 8 edges in flight

__global__ __launch_bounds__(256) void k_agg2(const __half* __restrict__ Zp,
                                              const int2* __restrict__ eew,
                                              const int* __restrict__ off,
                                              const int* __restrict__ cnt,
                                              const float* __restrict__ dinv,
                                              const float* __restrict__ b2,
                                              float* __restrict__ Out, int n) {
    int node = blockIdx.x * 4 + (threadIdx.x >> 6);
    int lane = threadIdx.x & 63;
    if (node >= n) return;
    int q = lane & 7, g = lane >> 3;
    float di = dinv[node];
    int start = off[node], total = cnt[node] + 1;

    float acc[8] = {0.f, 0.f, 0.f, 0.f, 0.f, 0.f, 0.f, 0.f};

    for (int base = 0; base < total; base += 8) {
        int sm = 0;
        float wm = 0.f;
        if (lane < 8) {
            int vj = base + lane;
            if (vj == 0) {
                sm = node; wm = di * di;
            } else if (vj < total) {
                int2 t = eew[start + vj - 1];
                sm = t.x; wm = __int_as_float(t.y);
            }
        }
        int s = __shfl(sm, g);
        float w = __shfl(wm, g);
        const uint4* rp = (const uint4*)(Zp + (size_t)s * ZP);
        uint4 v = rp[q];
        float2 f;
        f = __half22float2(*(const __half2*)&v.x);
        acc[0] = fmaf(f.x, w, acc[0]); acc[1] = fmaf(f.y, w, acc[1]);
        f = __half22float2(*(const __half2*)&v.y);
        acc[2] = fmaf(f.x, w, acc[2]); acc[3] = fmaf(f.y, w, acc[3]);
        f = __half22float2(*(const __half2*)&v.z);
        acc[4] = fmaf(f.x, w, acc[4]); acc[5] = fmaf(f.y, w, acc[5]);
        f = __half22float2(*(const __half2*)&v.w);
        acc[6] = fmaf(f.x, w, acc[6]); acc[7] = fmaf(f.y, w, acc[7]);
    }

#pragma unroll
    for (int o = 8; o <= 32; o <<= 1)
#pragma unroll
        for (int i = 0; i < 8; i++) acc[i] += __shfl_xor(acc[i], o);

    // every lane now holds classes q*8 .. q*8+7 (valid iff q<5)
    bool valid = (q < 5);
    float v[8];
    float m = -INFINITY;
#pragma unroll
    for (int i = 0; i < 8; i++) {
        v[i] = valid ? acc[i] + b2[q * 8 + i] : -INFINITY;
        m = fmaxf(m, v[i]);
    }
#pragma unroll
    for (int o = 1; o <= 4; o <<= 1) m = fmaxf(m, __shfl_xor(m, o));
    float ssum = 0.f;
#pragma unroll
    for (int i = 0; i < 8; i++)
        if (valid) ssum += __expf(v[i] - m);
#pragma unroll
    for (int o = 1; o <= 4; o <<= 1) ssum += __shfl_xor(ssum, o);
    float lse = m + logf(ssum);

    if (lane < 5) {  // q==lane, groups replicate
        float4 w0 = make_float4(v[0] - lse, v[1] - lse, v[2] - lse, v[3] - lse);
        float4 w1 = make_float4(v[4] - lse, v[5] - lse, v[6] - lse, v[7] - lse);
        float* op = Out + (size_t)node * NCLS + lane * 8;
        *(float4*)op = w0;
        *(float4*)(op + 4) = w1;
    }
}

// ---------------- launch ----------------

extern "C" void kernel_launch(void* const* d_in, const int* in_sizes, int n_in,
                              void* d_out, int out_size, void* d_ws, size_t ws_size,
                              hipStream_t stream) {
    const float* x  = (const float*)d_in[0];
    const int* ei   = (const int*)d_in[1];
    const float* W1 = (const float*)d_in[2];
    const float* b1 = (const float*)d_in[3];
    const float* W2 = (const float*)d_in[4];
    const float* b2 = (const float*)d_in[5];
    float* out = (float*)d_out;

    const int n = in_sizes[0] / FIN;   // 100000
    const int E = in_sizes[1] / 2;     // 1600000
    const int* src = ei;
    const int* dst = ei + E;

    char* w = (char*)d_ws;
    auto alloc = [&](size_t bytes) {
        char* p = w;
        w += (bytes + 255) & ~(size_t)255;
        return p;
    };
    int* cnt     = (int*)alloc((size_t)n * 4);
    int* off     = (int*)alloc((size_t)n * 4);
    int* cursor  = (int*)alloc((size_t)n * 4);
    int* bsum    = (int*)alloc(512);
    float* dinv  = (float*)alloc((size_t)n * 4);
    int2* eew    = (int2*)alloc((size_t)E * 8);
    ushort* wt   = (ushort*)alloc((size_t)FIN * HID * 2);
    __half* H16  = (__half*)alloc((size_t)n * HID * 2);
    __half* H2   = (__half*)alloc((size_t)n * HID * 2);
    __half* Zp   = (__half*)alloc((size_t)n * ZP * 2);

    const int nb = (n + 1023) / 1024;

    k_w1_cvt<<<(FIN * HID) / 256, 256, 0, stream>>>(W1, wt);

    // CSR + dinv + edge weights
    k_zero_int<<<(n + 255) / 256, 256, 0, stream>>>(cnt, n);
    k_hist<<<(E + 255) / 256, 256, 0, stream>>>(dst, E, cnt);
    k_scan1<<<nb, 1024, 0, stream>>>(cnt, off, bsum, n);
    k_scan2<<<1, 64, 0, stream>>>(bsum, nb);
    k_scan3<<<(n + 255) / 256, 256, 0, stream>>>(off, cnt, bsum, cursor, dinv, n);
    k_scatter<<<(E + 255) / 256, 256, 0, stream>>>(src, dst, E, cursor, dinv, eew);

    // layer 1
    k_gemm1<<<(n + 63) / 64, 256, 0, stream>>>(x, wt, H16, n);
    k_agg1<<<(n + 3) / 4, 256, 0, stream>>>(H16, eew, off, cnt, dinv, b1, H2, n);

    // layer 2 + log_softmax
    k_gemm2<<<(n + 63) / 64, 256, 0, stream>>>(H2, W2, Zp, n);
    k_agg2<<<(n + 3) / 4, 256, 0, stream>>>(Zp, eew, off, cnt, dinv, b2, out, n);
}

// Round 4
// 382.778 us; speedup vs baseline: 3.4295x; 1.2297x over previous
//
#include <hip/hip_runtime.h>
#include <hip/hip_fp16.h>
#include <math.h>

#define FIN 256
#define HID 128
#define NCLS 40
#define ZP 40

typedef __attribute__((ext_vector_type(8))) short short8_t;
typedef __attribute__((ext_vector_type(8))) _Float16 half8_t;
typedef __attribute__((ext_vector_type(4))) float f32x4;

static __device__ __forceinline__ ushort f2bf(float f) {
    unsigned u = __float_as_uint(f);
    u += 0x7FFF + ((u >> 16) & 1);
    return (ushort)(u >> 16);
}

// ---------------- CSR build ----------------

__global__ void k_zero_int(int* p, int n) {
    int i = blockIdx.x * blockDim.x + threadIdx.x;
    if (i < n) p[i] = 0;
}

__global__ void k_hist(const int* __restrict__ dst, int E, int* __restrict__ cnt) {
    int e = blockIdx.x * blockDim.x + threadIdx.x;
    if (e < E) atomicAdd(&cnt[dst[e]], 1);
}

__global__ __launch_bounds__(1024) void k_scan1(const int* __restrict__ cnt, int* __restrict__ off,
                                                int* __restrict__ bsum, int n) {
    __shared__ int sm[1024];
    int t = threadIdx.x;
    int i = blockIdx.x * 1024 + t;
    int v = (i < n) ? cnt[i] : 0;
    sm[t] = v;
    __syncthreads();
    for (int o = 1; o < 1024; o <<= 1) {
        int u = (t >= o) ? sm[t - o] : 0;
        __syncthreads();
        sm[t] += u;
        __syncthreads();
    }
    if (i < n) off[i] = sm[t];
    if (t == 1023) bsum[blockIdx.x] = sm[1023];
}

__global__ void k_scan2(int* __restrict__ bsum, int nb) {
    int lane = threadIdx.x;
    int v0 = (lane < nb) ? bsum[lane] : 0;
    int v1 = (64 + lane < nb) ? bsum[64 + lane] : 0;
    int o0 = v0, o1 = v1;
    for (int o = 1; o < 64; o <<= 1) {
        int t = __shfl_up(v0, o);
        if (lane >= o) v0 += t;
    }
    int tot0 = __shfl(v0, 63);
    for (int o = 1; o < 64; o <<= 1) {
        int t = __shfl_up(v1, o);
        if (lane >= o) v1 += t;
    }
    v1 += tot0;
    if (lane < nb) bsum[lane] = v0 - o0;
    if (64 + lane < nb) bsum[64 + lane] = v1 - o1;
}

__global__ void k_scan3(int* __restrict__ off, const int* __restrict__ cnt,
                        const int* __restrict__ bsum, int* __restrict__ cursor,
                        float* __restrict__ dinv, int n) {
    int i = blockIdx.x * blockDim.x + threadIdx.x;
    if (i < n) {
        int excl = off[i] - cnt[i] + bsum[i >> 10];
        off[i] = excl;
        cursor[i] = excl;
        dinv[i] = rsqrtf((float)(cnt[i] + 1));
    }
}

// scatter src + precomputed edge weight, packed int2 {src, bits(w)}
__global__ void k_scatter(const int* __restrict__ src, const int* __restrict__ dst, int E,
                          int* __restrict__ cursor, const float* __restrict__ dinv,
                          int2* __restrict__ eew) {
    int e = blockIdx.x * blockDim.x + threadIdx.x;
    if (e < E) {
        int d = dst[e], s = src[e];
        int pos = atomicAdd(&cursor[d], 1);
        eew[pos] = make_int2(s, __float_as_int(dinv[s] * dinv[d]));
    }
}

// ---------------- weight conversions ----------------

__global__ void k_w1_cvt(const float* __restrict__ W1, ushort* __restrict__ Wt) {
    int idx = blockIdx.x * 256 + threadIdx.x;  // 128*256
    int c = idx >> 8, k = idx & 255;
    Wt[idx] = f2bf(W1[(size_t)k * HID + c]);
}

// W2 [128][40] f32 -> W2t [48][128] f16 (zero-padded cols)
__global__ void k_w2_cvt(const float* __restrict__ W2, __half* __restrict__ W2t) {
    int idx = blockIdx.x * 256 + threadIdx.x;  // 48*128 = 6144
    int c = idx >> 7, k = idx & 127;
    W2t[idx] = __float2half((c < NCLS) ? W2[(size_t)k * NCLS + c] : 0.f);
}

// ---------------- GEMM1 (MFMA bf16): H16 = fp16(X @ W1) ----------------

__global__ __launch_bounds__(256) void k_gemm1(const float* __restrict__ X,
                                               const ushort* __restrict__ Wt,
                                               __half* __restrict__ H16, int M) {
    __shared__ uint4 wlds[128 * 32];  // 64 KB, chunk-swizzled [col][32 chunks of 8 bf16]
    int tid = threadIdx.x;
    const uint4* wg = (const uint4*)Wt;
#pragma unroll
    for (int i = 0; i < 16; i++) {
        int e = tid + i * 256;
        int r = e >> 5, ch = e & 31;
        wlds[r * 32 + (ch ^ (r & 7))] = wg[e];
    }
    __syncthreads();

    int wid = tid >> 6, lane = tid & 63;
    int q = lane & 15, kg = lane >> 4;
    int row = blockIdx.x * 64 + wid * 16 + q;
    int lrow = min(row, M - 1);
    const float* xr = X + (size_t)lrow * FIN;

    f32x4 acc[8];
#pragma unroll
    for (int c = 0; c < 8; c++) acc[c] = (f32x4){0.f, 0.f, 0.f, 0.f};

#pragma unroll
    for (int kt = 0; kt < 8; kt++) {
        int k0 = kt * 32 + kg * 8;
        float4 f0 = *(const float4*)(xr + k0);
        float4 f1 = *(const float4*)(xr + k0 + 4);
        short8_t a;
        a[0] = (short)f2bf(f0.x); a[1] = (short)f2bf(f0.y);
        a[2] = (short)f2bf(f0.z); a[3] = (short)f2bf(f0.w);
        a[4] = (short)f2bf(f1.x); a[5] = (short)f2bf(f1.y);
        a[6] = (short)f2bf(f1.z); a[7] = (short)f2bf(f1.w);
        int ch = kt * 4 + kg;
#pragma unroll
        for (int c = 0; c < 8; c++) {
            int col = c * 16 + q;
            short8_t b = *(const short8_t*)&wlds[col * 32 + (ch ^ (col & 7))];
            acc[c] = __builtin_amdgcn_mfma_f32_16x16x32_bf16(a, b, acc[c], 0, 0, 0);
        }
    }

    int r0 = blockIdx.x * 64 + wid * 16 + kg * 4;  // C/D: row=(lane>>4)*4+i, col=lane&15
#pragma unroll
    for (int c = 0; c < 8; c++) {
        int col = c * 16 + q;
#pragma unroll
        for (int i = 0; i < 4; i++) {
            int r = r0 + i;
            if (r < M) H16[(size_t)r * HID + col] = __float2half(acc[c][i]);
        }
    }
}

// ---------------- agg1: H2 = fp16(relu(b1 + sum w*H16[s])) ----------------
// one wave per node; 4 groups of 16 lanes, 4 edges in flight

__global__ __launch_bounds__(256) void k_agg1(const __half* __restrict__ H16,
                                              const int2* __restrict__ eew,
                                              const int* __restrict__ off,
                                              const int* __restrict__ cnt,
                                              const float* __restrict__ dinv,
                                              const float* __restrict__ b1,
                                              __half* __restrict__ H2, int n) {
    int node = blockIdx.x * 4 + (threadIdx.x >> 6);
    int lane = threadIdx.x & 63;
    if (node >= n) return;
    int q = lane & 15, g = lane >> 4;
    float di = dinv[node];
    int start = off[node], total = cnt[node] + 1;  // virtual edge 0 = self-loop

    float acc[8] = {0.f, 0.f, 0.f, 0.f, 0.f, 0.f, 0.f, 0.f};

    for (int base = 0; base < total; base += 4) {
        int sm = 0;
        float wm = 0.f;
        if (lane < 4) {
            int vj = base + lane;
            if (vj == 0) {
                sm = node; wm = di * di;
            } else if (vj < total) {
                int2 t = eew[start + vj - 1];
                sm = t.x; wm = __int_as_float(t.y);
            }
        }
        int s = __shfl(sm, g);
        float w = __shfl(wm, g);
        const uint4* rp = (const uint4*)(H16 + (size_t)s * HID);
        uint4 v = rp[q];
        float2 f;
        f = __half22float2(*(const __half2*)&v.x);
        acc[0] = fmaf(f.x, w, acc[0]); acc[1] = fmaf(f.y, w, acc[1]);
        f = __half22float2(*(const __half2*)&v.y);
        acc[2] = fmaf(f.x, w, acc[2]); acc[3] = fmaf(f.y, w, acc[3]);
        f = __half22float2(*(const __half2*)&v.z);
        acc[4] = fmaf(f.x, w, acc[4]); acc[5] = fmaf(f.y, w, acc[5]);
        f = __half22float2(*(const __half2*)&v.w);
        acc[6] = fmaf(f.x, w, acc[6]); acc[7] = fmaf(f.y, w, acc[7]);
    }

#pragma unroll
    for (int o = 16; o <= 32; o <<= 1)
#pragma unroll
        for (int i = 0; i < 8; i++) acc[i] += __shfl_xor(acc[i], o);

    if (lane < 16) {
        float r[8];
#pragma unroll
        for (int i = 0; i < 8; i++) r[i] = fmaxf(acc[i] + b1[q * 8 + i], 0.f);
        __half2 p0 = __floats2half2_rn(r[0], r[1]);
        __half2 p1 = __floats2half2_rn(r[2], r[3]);
        __half2 p2 = __floats2half2_rn(r[4], r[5]);
        __half2 p3 = __floats2half2_rn(r[6], r[7]);
        uint4 o4;
        o4.x = *(unsigned*)&p0; o4.y = *(unsigned*)&p1;
        o4.z = *(unsigned*)&p2; o4.w = *(unsigned*)&p3;
        *(uint4*)(H2 + (size_t)node * HID + q * 8) = o4;
    }
}

// ---------------- GEMM2 (MFMA fp16, no LDS): Zp = fp16(H2 @ W2) ----------------
// block = 256 thr (4 waves), 64 rows/block; each wave: 16 rows x 48 cols

__global__ __launch_bounds__(256) void k_gemm2(const __half* __restrict__ H2,
                                               const __half* __restrict__ W2t,
                                               __half* __restrict__ Zp, int M) {
    int tid = threadIdx.x;
    int wid = tid >> 6, lane = tid & 63;
    int q = lane & 15, kg = lane >> 4;
    int row = blockIdx.x * 64 + wid * 16 + q;
    int lrow = min(row, M - 1);
    const __half* hr = H2 + (size_t)lrow * HID;

    half8_t a[4];
#pragma unroll
    for (int kt = 0; kt < 4; kt++) a[kt] = *(const half8_t*)(hr + kt * 32 + kg * 8);

    f32x4 acc[3];
#pragma unroll
    for (int c = 0; c < 3; c++) acc[c] = (f32x4){0.f, 0.f, 0.f, 0.f};

#pragma unroll
    for (int c = 0; c < 3; c++) {
        const __half* wc = W2t + (size_t)(c * 16 + q) * HID + kg * 8;
#pragma unroll
        for (int kt = 0; kt < 4; kt++) {
            half8_t b = *(const half8_t*)(wc + kt * 32);
            acc[c] = __builtin_amdgcn_mfma_f32_16x16x32_f16(a[kt], b, acc[c], 0, 0, 0);
        }
    }

    int r0 = blockIdx.x * 64 + wid * 16 + kg * 4;
#pragma unroll
    for (int c = 0; c < 3; c++) {
        int col = c * 16 + q;
        if (col < NCLS) {
#pragma unroll
            for (int i = 0; i < 4; i++) {
                int r = r0 + i;
                if (r < M) Zp[(size_t)r * ZP + col] = __float2half(acc[c][i]);
            }
        }
    }
}

// ---------------- agg2 + bias + log_softmax ----------------
// one wave per node; 8 groups of 8 lanes, 8 edges in flight; rows are 40 halfs (80 B)

__global__ __launch_bounds__(256) void k_agg2(const __half* __restrict__ Zp,
                                              const int2* __restrict__ eew,
                                              const int* __restrict__ off,
                                              const int* __restrict__ cnt,
                                              const float* __restrict__ dinv,
                                              const float* __restrict__ b2,
                                              float* __restrict__ Out, int n) {
    int node = blockIdx.x * 4 + (threadIdx.x >> 6);
    int lane = threadIdx.x & 63;
    if (node >= n) return;
    int q = lane & 7, g = lane >> 3;
    float di = dinv[node];
    int start = off[node], total = cnt[node] + 1;

    float acc[8] = {0.f, 0.f, 0.f, 0.f, 0.f, 0.f, 0.f, 0.f};

    for (int base = 0; base < total; base += 8) {
        int sm = 0;
        float wm = 0.f;
        if (lane < 8) {
            int vj = base + lane;
            if (vj == 0) {
                sm = node; wm = di * di;
            } else if (vj < total) {
                int2 t = eew[start + vj - 1];
                sm = t.x; wm = __int_as_float(t.y);
            }
        }
        int s = __shfl(sm, g);
        float w = __shfl(wm, g);
        uint4 v = make_uint4(0u, 0u, 0u, 0u);
        if (q < 5) v = *(const uint4*)(Zp + (size_t)s * ZP + q * 8);
        float2 f;
        f = __half22float2(*(const __half2*)&v.x);
        acc[0] = fmaf(f.x, w, acc[0]); acc[1] = fmaf(f.y, w, acc[1]);
        f = __half22float2(*(const __half2*)&v.y);
        acc[2] = fmaf(f.x, w, acc[2]); acc[3] = fmaf(f.y, w, acc[3]);
        f = __half22float2(*(const __half2*)&v.z);
        acc[4] = fmaf(f.x, w, acc[4]); acc[5] = fmaf(f.y, w, acc[5]);
        f = __half22float2(*(const __half2*)&v.w);
        acc[6] = fmaf(f.x, w, acc[6]); acc[7] = fmaf(f.y, w, acc[7]);
    }

#pragma unroll
    for (int o = 8; o <= 32; o <<= 1)
#pragma unroll
        for (int i = 0; i < 8; i++) acc[i] += __shfl_xor(acc[i], o);

    // every lane now holds classes q*8 .. q*8+7 (valid iff q<5)
    bool valid = (q < 5);
    float v[8];
    float m = -INFINITY;
#pragma unroll
    for (int i = 0; i < 8; i++) {
        v[i] = valid ? acc[i] + b2[q * 8 + i] : -INFINITY;
        m = fmaxf(m, v[i]);
    }
#pragma unroll
    for (int o = 1; o <= 4; o <<= 1) m = fmaxf(m, __shfl_xor(m, o));
    float ssum = 0.f;
#pragma unroll
    for (int i = 0; i < 8; i++)
        if (valid) ssum += __expf(v[i] - m);
#pragma unroll
    for (int o = 1; o <= 4; o <<= 1) ssum += __shfl_xor(ssum, o);
    float lse = m + logf(ssum);

    if (lane < 5) {  // q==lane, groups replicate
        float4 w0 = make_float4(v[0] - lse, v[1] - lse, v[2] - lse, v[3] - lse);
        float4 w1 = make_float4(v[4] - lse, v[5] - lse, v[6] - lse, v[7] - lse);
        float* op = Out + (size_t)node * NCLS + lane * 8;
        *(float4*)op = w0;
        *(float4*)(op + 4) = w1;
    }
}

// ---------------- launch ----------------

extern "C" void kernel_launch(void* const* d_in, const int* in_sizes, int n_in,
                              void* d_out, int out_size, void* d_ws, size_t ws_size,
                              hipStream_t stream) {
    const float* x  = (const float*)d_in[0];
    const int* ei   = (const int*)d_in[1];
    const float* W1 = (const float*)d_in[2];
    const float* b1 = (const float*)d_in[3];
    const float* W2 = (const float*)d_in[4];
    const float* b2 = (const float*)d_in[5];
    float* out = (float*)d_out;

    const int n = in_sizes[0] / FIN;   // 100000
    const int E = in_sizes[1] / 2;     // 1600000
    const int* src = ei;
    const int* dst = ei + E;

    char* w = (char*)d_ws;
    auto alloc = [&](size_t bytes) {
        char* p = w;
        w += (bytes + 255) & ~(size_t)255;
        return p;
    };
    int* cnt     = (int*)alloc((size_t)n * 4);
    int* off     = (int*)alloc((size_t)n * 4);
    int* cursor  = (int*)alloc((size_t)n * 4);
    int* bsum    = (int*)alloc(512);
    float* dinv  = (float*)alloc((size_t)n * 4);
    int2* eew    = (int2*)alloc((size_t)E * 8);
    ushort* wt   = (ushort*)alloc((size_t)FIN * HID * 2);
    __half* w2t  = (__half*)alloc((size_t)48 * HID * 2);
    __half* H16  = (__half*)alloc((size_t)n * HID * 2);
    __half* H2   = (__half*)alloc((size_t)n * HID * 2);
    __half* Zp   = (__half*)alloc((size_t)n * ZP * 2);

    const int nb = (n + 1023) / 1024;

    k_w1_cvt<<<(FIN * HID) / 256, 256, 0, stream>>>(W1, wt);
    k_w2_cvt<<<(48 * HID) / 256, 256, 0, stream>>>(W2, w2t);

    // CSR + dinv + edge weights
    k_zero_int<<<(n + 255) / 256, 256, 0, stream>>>(cnt, n);
    k_hist<<<(E + 255) / 256, 256, 0, stream>>>(dst, E, cnt);
    k_scan1<<<nb, 1024, 0, stream>>>(cnt, off, bsum, n);
    k_scan2<<<1, 64, 0, stream>>>(bsum, nb);
    k_scan3<<<(n + 255) / 256, 256, 0, stream>>>(off, cnt, bsum, cursor, dinv, n);
    k_scatter<<<(E + 255) / 256, 256, 0, stream>>>(src, dst, E, cursor, dinv, eew);

    // layer 1
    k_gemm1<<<(n + 63) / 64, 256, 0, stream>>>(x, wt, H16, n);
    k_agg1<<<(n + 3) / 4, 256, 0, stream>>>(H16, eew, off, cnt, dinv, b1, H2, n);

    // layer 2 + log_softmax
    k_gemm2<<<(n + 63) / 64, 256, 0, stream>>>(H2, w2t, Zp, n);
    k_agg2<<<(n + 3) / 4, 256, 0, stream>>>(Zp, eew, off, cnt, dinv, b2, out, n);
}

// Round 5
// 333.510 us; speedup vs baseline: 3.9362x; 1.1477x over previous
//
#include <hip/hip_runtime.h>
#include <hip/hip_fp16.h>
#include <math.h>

#define FIN 256
#define HID 128
#define NCLS 40
#define ZP 40
#define BKT_SHIFT 9
#define BKT_SZ 512
#define CHUNK 2048

typedef __attribute__((ext_vector_type(8))) short short8_t;
typedef __attribute__((ext_vector_type(8))) _Float16 half8_t;
typedef __attribute__((ext_vector_type(4))) float f32x4;

static __device__ __forceinline__ ushort f2bf(float f) {
    unsigned u = __float_as_uint(f);
    u += 0x7FFF + ((u >> 16) & 1);
    return (ushort)(u >> 16);
}

// ---------------- CSR build: hist + node-level scan ----------------

__global__ void k_zero_int(int* p, int n) {
    int i = blockIdx.x * blockDim.x + threadIdx.x;
    if (i < n) p[i] = 0;
}

__global__ void k_hist(const int* __restrict__ dst, int E, int* __restrict__ cnt) {
    int e = blockIdx.x * blockDim.x + threadIdx.x;
    if (e < E) atomicAdd(&cnt[dst[e]], 1);
}

__global__ __launch_bounds__(1024) void k_scan1(const int* __restrict__ cnt, int* __restrict__ off,
                                                int* __restrict__ bsum, int n) {
    __shared__ int sm[1024];
    int t = threadIdx.x;
    int i = blockIdx.x * 1024 + t;
    int v = (i < n) ? cnt[i] : 0;
    sm[t] = v;
    __syncthreads();
    for (int o = 1; o < 1024; o <<= 1) {
        int u = (t >= o) ? sm[t - o] : 0;
        __syncthreads();
        sm[t] += u;
        __syncthreads();
    }
    if (i < n) off[i] = sm[t];
    if (t == 1023) bsum[blockIdx.x] = sm[1023];
}

__global__ void k_scan2(int* __restrict__ bsum, int nb) {
    int lane = threadIdx.x;
    int v0 = (lane < nb) ? bsum[lane] : 0;
    int v1 = (64 + lane < nb) ? bsum[64 + lane] : 0;
    int o0 = v0, o1 = v1;
    for (int o = 1; o < 64; o <<= 1) {
        int t = __shfl_up(v0, o);
        if (lane >= o) v0 += t;
    }
    int tot0 = __shfl(v0, 63);
    for (int o = 1; o < 64; o <<= 1) {
        int t = __shfl_up(v1, o);
        if (lane >= o) v1 += t;
    }
    v1 += tot0;
    if (lane < nb) bsum[lane] = v0 - o0;
    if (64 + lane < nb) bsum[64 + lane] = v1 - o1;
}

__global__ void k_scan3(int* __restrict__ off, const int* __restrict__ cnt,
                        const int* __restrict__ bsum, float* __restrict__ dinv, int n) {
    int i = blockIdx.x * blockDim.x + threadIdx.x;
    if (i < n) {
        int excl = off[i] - cnt[i] + bsum[i >> 10];
        off[i] = excl;
        dinv[i] = rsqrtf((float)(cnt[i] + 1));
    }
}

// bucket region starts + cursors (nbk+1 entries; nbk <= 255)
__global__ void k_binit(const int* __restrict__ off, int* __restrict__ boff,
                        int* __restrict__ bcur, int n, int E, int nbk) {
    int t = threadIdx.x;
    if (t <= nbk) {
        int idx = t << BKT_SHIFT;
        int v = (idx >= n) ? E : off[idx];
        boff[t] = v;
        if (t < nbk) bcur[t] = v;
    }
}

// ---------------- phase 1: bucketize edges by dst>>9 (LDS counting sort per chunk) ----------------

__global__ __launch_bounds__(256) void k_bucketize(const int* __restrict__ src,
                                                   const int* __restrict__ dst, int E,
                                                   int* __restrict__ bcur,
                                                   int2* __restrict__ ebkt, int nbk) {
    __shared__ int hist[256];
    __shared__ int scanb[256];
    __shared__ int base[256];
    __shared__ int gbase[256];
    __shared__ int2 stage[CHUNK];
    int t = threadIdx.x;
    int e0 = blockIdx.x * CHUNK;
    int cntc = min(CHUNK, E - e0);
    hist[t] = 0;
    __syncthreads();

    int s_[8], d_[8], bk_[8], rk_[8];
#pragma unroll
    for (int i = 0; i < 8; i++) {
        int j = t + i * 256;
        if (j < cntc) {
            int s = src[e0 + j], d = dst[e0 + j];
            s_[i] = s; d_[i] = d;
            bk_[i] = d >> BKT_SHIFT;
            rk_[i] = atomicAdd(&hist[bk_[i]], 1);
        } else {
            bk_[i] = -1;
        }
    }
    __syncthreads();

    // inclusive scan of hist -> scanb
    scanb[t] = hist[t];
    __syncthreads();
    for (int o = 1; o < 256; o <<= 1) {
        int u = (t >= o) ? scanb[t - o] : 0;
        __syncthreads();
        scanb[t] += u;
        __syncthreads();
    }
    base[t] = scanb[t] - hist[t];  // exclusive within-chunk base
    if (t < nbk && hist[t] > 0) gbase[t] = atomicAdd(&bcur[t], hist[t]);
    __syncthreads();

    // LDS scatter into bucket-grouped order
#pragma unroll
    for (int i = 0; i < 8; i++) {
        if (bk_[i] >= 0) stage[base[bk_[i]] + rk_[i]] = make_int2(s_[i], d_[i]);
    }
    __syncthreads();

    // linear write-out (runs are contiguous in global)
#pragma unroll
    for (int i = 0; i < 8; i++) {
        int j = t + i * 256;
        if (j < cntc) {
            int2 e = stage[j];
            int bk = e.y >> BKT_SHIFT;
            ebkt[gbase[bk] + (j - base[bk])] = e;
        }
    }
}

// ---------------- phase 2: within-bucket sort to final CSR positions ----------------
// one block per bucket; eew window is block-private -> L2-coalesced writes

__global__ __launch_bounds__(512) void k_sortbkt(const int2* __restrict__ ebkt,
                                                 const int* __restrict__ boff,
                                                 const int* __restrict__ off,
                                                 const float* __restrict__ dinv,
                                                 int2* __restrict__ eew, int n) {
    __shared__ int cur[BKT_SZ];
    __shared__ float ldin[BKT_SZ];
    int b = blockIdx.x, t = threadIdx.x;
    int n0 = b << BKT_SHIFT;
    int nn = min(BKT_SZ, n - n0);
    for (int i = t; i < nn; i += 512) {
        cur[i] = off[n0 + i];
        ldin[i] = dinv[n0 + i];
    }
    __syncthreads();
    int e0 = boff[b], e1 = boff[b + 1];
    for (int e = e0 + t; e < e1; e += 512) {
        int2 ed = ebkt[e];
        int s = ed.x, d = ed.y - n0;
        float w = dinv[s] * ldin[d];
        int pos = atomicAdd(&cur[d], 1);
        eew[pos] = make_int2(s, __float_as_int(w));
    }
}

// ---------------- weight conversions ----------------

__global__ void k_w1_cvt(const float* __restrict__ W1, ushort* __restrict__ Wt) {
    int idx = blockIdx.x * 256 + threadIdx.x;  // 128*256
    int c = idx >> 8, k = idx & 255;
    Wt[idx] = f2bf(W1[(size_t)k * HID + c]);
}

// W2 [128][40] f32 -> W2t [48][128] f16 (zero-padded cols)
__global__ void k_w2_cvt(const float* __restrict__ W2, __half* __restrict__ W2t) {
    int idx = blockIdx.x * 256 + threadIdx.x;  // 48*128 = 6144
    int c = idx >> 7, k = idx & 127;
    W2t[idx] = __float2half((c < NCLS) ? W2[(size_t)k * NCLS + c] : 0.f);
}

// ---------------- GEMM1 (MFMA bf16): H16 = fp16(X @ W1) ----------------

__global__ __launch_bounds__(256) void k_gemm1(const float* __restrict__ X,
                                               const ushort* __restrict__ Wt,
                                               __half* __restrict__ H16, int M) {
    __shared__ uint4 wlds[128 * 32];  // 64 KB, chunk-swizzled [col][32 chunks of 8 bf16]
    int tid = threadIdx.x;
    const uint4* wg = (const uint4*)Wt;
#pragma unroll
    for (int i = 0; i < 16; i++) {
        int e = tid + i * 256;
        int r = e >> 5, ch = e & 31;
        wlds[r * 32 + (ch ^ (r & 7))] = wg[e];
    }
    __syncthreads();

    int wid = tid >> 6, lane = tid & 63;
    int q = lane & 15, kg = lane >> 4;
    int row = blockIdx.x * 64 + wid * 16 + q;
    int lrow = min(row, M - 1);
    const float* xr = X + (size_t)lrow * FIN;

    f32x4 acc[8];
#pragma unroll
    for (int c = 0; c < 8; c++) acc[c] = (f32x4){0.f, 0.f, 0.f, 0.f};

#pragma unroll
    for (int kt = 0; kt < 8; kt++) {
        int k0 = kt * 32 + kg * 8;
        float4 f0 = *(const float4*)(xr + k0);
        float4 f1 = *(const float4*)(xr + k0 + 4);
        short8_t a;
        a[0] = (short)f2bf(f0.x); a[1] = (short)f2bf(f0.y);
        a[2] = (short)f2bf(f0.z); a[3] = (short)f2bf(f0.w);
        a[4] = (short)f2bf(f1.x); a[5] = (short)f2bf(f1.y);
        a[6] = (short)f2bf(f1.z); a[7] = (short)f2bf(f1.w);
        int ch = kt * 4 + kg;
#pragma unroll
        for (int c = 0; c < 8; c++) {
            int col = c * 16 + q;
            short8_t b = *(const short8_t*)&wlds[col * 32 + (ch ^ (col & 7))];
            acc[c] = __builtin_amdgcn_mfma_f32_16x16x32_bf16(a, b, acc[c], 0, 0, 0);
        }
    }

    int r0 = blockIdx.x * 64 + wid * 16 + kg * 4;  // C/D: row=(lane>>4)*4+i, col=lane&15
#pragma unroll
    for (int c = 0; c < 8; c++) {
        int col = c * 16 + q;
#pragma unroll
        for (int i = 0; i < 4; i++) {
            int r = r0 + i;
            if (r < M) H16[(size_t)r * HID + col] = __float2half(acc[c][i]);
        }
    }
}

// ---------------- agg1: H2 = fp16(relu(b1 + sum w*H16[s])) ----------------
// one wave per node; 4 groups of 16 lanes, 4 edges in flight

__global__ __launch_bounds__(256) void k_agg1(const __half* __restrict__ H16,
                                              const int2* __restrict__ eew,
                                              const int* __restrict__ off,
                                              const int* __restrict__ cnt,
                                              const float* __restrict__ dinv,
                                              const float* __restrict__ b1,
                                              __half* __restrict__ H2, int n) {
    int node = blockIdx.x * 4 + (threadIdx.x >> 6);
    int lane = threadIdx.x & 63;
    if (node >= n) return;
    int q = lane & 15, g = lane >> 4;
    float di = dinv[node];
    int start = off[node], total = cnt[node] + 1;  // virtual edge 0 = self-loop

    float acc[8] = {0.f, 0.f, 0.f, 0.f, 0.f, 0.f, 0.f, 0.f};

    for (int base = 0; base < total; base += 4) {
        int sm = 0;
        float wm = 0.f;
        if (lane < 4) {
            int vj = base + lane;
            if (vj == 0) {
                sm = node; wm = di * di;
            } else if (vj < total) {
                int2 t = eew[start + vj - 1];
                sm = t.x; wm = __int_as_float(t.y);
            }
        }
        int s = __shfl(sm, g);
        float w = __shfl(wm, g);
        const uint4* rp = (const uint4*)(H16 + (size_t)s * HID);
        uint4 v = rp[q];
        float2 f;
        f = __half22float2(*(const __half2*)&v.x);
        acc[0] = fmaf(f.x, w, acc[0]); acc[1] = fmaf(f.y, w, acc[1]);
        f = __half22float2(*(const __half2*)&v.y);
        acc[2] = fmaf(f.x, w, acc[2]); acc[3] = fmaf(f.y, w, acc[3]);
        f = __half22float2(*(const __half2*)&v.z);
        acc[4] = fmaf(f.x, w, acc[4]); acc[5] = fmaf(f.y, w, acc[5]);
        f = __half22float2(*(const __half2*)&v.w);
        acc[6] = fmaf(f.x, w, acc[6]); acc[7] = fmaf(f.y, w, acc[7]);
    }

#pragma unroll
    for (int o = 16; o <= 32; o <<= 1)
#pragma unroll
        for (int i = 0; i < 8; i++) acc[i] += __shfl_xor(acc[i], o);

    if (lane < 16) {
        float r[8];
#pragma unroll
        for (int i = 0; i < 8; i++) r[i] = fmaxf(acc[i] + b1[q * 8 + i], 0.f);
        __half2 p0 = __floats2half2_rn(r[0], r[1]);
        __half2 p1 = __floats2half2_rn(r[2], r[3]);
        __half2 p2 = __floats2half2_rn(r[4], r[5]);
        __half2 p3 = __floats2half2_rn(r[6], r[7]);
        uint4 o4;
        o4.x = *(unsigned*)&p0; o4.y = *(unsigned*)&p1;
        o4.z = *(unsigned*)&p2; o4.w = *(unsigned*)&p3;
        *(uint4*)(H2 + (size_t)node * HID + q * 8) = o4;
    }
}

// ---------------- GEMM2 (MFMA fp16, no LDS): Zp = fp16(H2 @ W2) ----------------

__global__ __launch_bounds__(256) void k_gemm2(const __half* __restrict__ H2,
                                               const __half* __restrict__ W2t,
                                               __half* __restrict__ Zp, int M) {
    int tid = threadIdx.x;
    int wid = tid >> 6, lane = tid & 63;
    int q = lane & 15, kg = lane >> 4;
    int row = blockIdx.x * 64 + wid * 16 + q;
    int lrow = min(row, M - 1);
    const __half* hr = H2 + (size_t)lrow * HID;

    half8_t a[4];
#pragma unroll
    for (int kt = 0; kt < 4; kt++) a[kt] = *(const half8_t*)(hr + kt * 32 + kg * 8);

    f32x4 acc[3];
#pragma unroll
    for (int c = 0; c < 3; c++) acc[c] = (f32x4){0.f, 0.f, 0.f, 0.f};

#pragma unroll
    for (int c = 0; c < 3; c++) {
        const __half* wc = W2t + (size_t)(c * 16 + q) * HID + kg * 8;
#pragma unroll
        for (int kt = 0; kt < 4; kt++) {
            half8_t b = *(const half8_t*)(wc + kt * 32);
            acc[c] = __builtin_amdgcn_mfma_f32_16x16x32_f16(a[kt], b, acc[c], 0, 0, 0);
        }
    }

    int r0 = blockIdx.x * 64 + wid * 16 + kg * 4;
#pragma unroll
    for (int c = 0; c < 3; c++) {
        int col = c * 16 + q;
        if (col < NCLS) {
#pragma unroll
            for (int i = 0; i < 4; i++) {
                int r = r0 + i;
                if (r < M) Zp[(size_t)r * ZP + col] = __float2half(acc[c][i]);
            }
        }
    }
}

// ---------------- agg2 + bias + log_softmax ----------------
// one wave per node; 8 groups of 8 lanes, 8 edges in flight; rows are 40 halfs (80 B)

__global__ __launch_bounds__(256) void k_agg2(const __half* __restrict__ Zp,
                                              const int2* __restrict__ eew,
                                              const int* __restrict__ off,
                                              const int* __restrict__ cnt,
                                              const float* __restrict__ dinv,
                                              const float* __restrict__ b2,
                                              float* __restrict__ Out, int n) {
    int node = blockIdx.x * 4 + (threadIdx.x >> 6);
    int lane = threadIdx.x & 63;
    if (node >= n) return;
    int q = lane & 7, g = lane >> 3;
    float di = dinv[node];
    int start = off[node], total = cnt[node] + 1;

    float acc[8] = {0.f, 0.f, 0.f, 0.f, 0.f, 0.f, 0.f, 0.f};

    for (int base = 0; base < total; base += 8) {
        int sm = 0;
        float wm = 0.f;
        if (lane < 8) {
            int vj = base + lane;
            if (vj == 0) {
                sm = node; wm = di * di;
            } else if (vj < total) {
                int2 t = eew[start + vj - 1];
                sm = t.x; wm = __int_as_float(t.y);
            }
        }
        int s = __shfl(sm, g);
        float w = __shfl(wm, g);
        uint4 v = make_uint4(0u, 0u, 0u, 0u);
        if (q < 5) v = *(const uint4*)(Zp + (size_t)s * ZP + q * 8);
        float2 f;
        f = __half22float2(*(const __half2*)&v.x);
        acc[0] = fmaf(f.x, w, acc[0]); acc[1] = fmaf(f.y, w, acc[1]);
        f = __half22float2(*(const __half2*)&v.y);
        acc[2] = fmaf(f.x, w, acc[2]); acc[3] = fmaf(f.y, w, acc[3]);
        f = __half22float2(*(const __half2*)&v.z);
        acc[4] = fmaf(f.x, w, acc[4]); acc[5] = fmaf(f.y, w, acc[5]);
        f = __half22float2(*(const __half2*)&v.w);
        acc[6] = fmaf(f.x, w, acc[6]); acc[7] = fmaf(f.y, w, acc[7]);
    }

#pragma unroll
    for (int o = 8; o <= 32; o <<= 1)
#pragma unroll
        for (int i = 0; i < 8; i++) acc[i] += __shfl_xor(acc[i], o);

    // every lane now holds classes q*8 .. q*8+7 (valid iff q<5)
    bool valid = (q < 5);
    float v[8];
    float m = -INFINITY;
#pragma unroll
    for (int i = 0; i < 8; i++) {
        v[i] = valid ? acc[i] + b2[q * 8 + i] : -INFINITY;
        m = fmaxf(m, v[i]);
    }
#pragma unroll
    for (int o = 1; o <= 4; o <<= 1) m = fmaxf(m, __shfl_xor(m, o));
    float ssum = 0.f;
#pragma unroll
    for (int i = 0; i < 8; i++)
        if (valid) ssum += __expf(v[i] - m);
#pragma unroll
    for (int o = 1; o <= 4; o <<= 1) ssum += __shfl_xor(ssum, o);
    float lse = m + logf(ssum);

    if (lane < 5) {  // q==lane, groups replicate
        float4 w0 = make_float4(v[0] - lse, v[1] - lse, v[2] - lse, v[3] - lse);
        float4 w1 = make_float4(v[4] - lse, v[5] - lse, v[6] - lse, v[7] - lse);
        float* op = Out + (size_t)node * NCLS + lane * 8;
        *(float4*)op = w0;
        *(float4*)(op + 4) = w1;
    }
}

// ---------------- launch ----------------

extern "C" void kernel_launch(void* const* d_in, const int* in_sizes, int n_in,
                              void* d_out, int out_size, void* d_ws, size_t ws_size,
                              hipStream_t stream) {
    const float* x  = (const float*)d_in[0];
    const int* ei   = (const int*)d_in[1];
    const float* W1 = (const float*)d_in[2];
    const float* b1 = (const float*)d_in[3];
    const float* W2 = (const float*)d_in[4];
    const float* b2 = (const float*)d_in[5];
    float* out = (float*)d_out;

    const int n = in_sizes[0] / FIN;   // 100000
    const int E = in_sizes[1] / 2;     // 1600000
    const int* src = ei;
    const int* dst = ei + E;
    const int nbk = (n + BKT_SZ - 1) >> BKT_SHIFT;  // 196

    char* w = (char*)d_ws;
    auto alloc = [&](size_t bytes) {
        char* p = w;
        w += (bytes + 255) & ~(size_t)255;
        return p;
    };
    int* cnt     = (int*)alloc((size_t)n * 4);
    int* off     = (int*)alloc((size_t)n * 4);
    int* bsum    = (int*)alloc(512);
    float* dinv  = (float*)alloc((size_t)n * 4);
    int* boff    = (int*)alloc((size_t)(nbk + 1) * 4);
    int* bcur    = (int*)alloc((size_t)nbk * 4);
    int2* ebkt   = (int2*)alloc((size_t)E * 8);
    int2* eew    = (int2*)alloc((size_t)E * 8);
    ushort* wt   = (ushort*)alloc((size_t)FIN * HID * 2);
    __half* w2t  = (__half*)alloc((size_t)48 * HID * 2);
    __half* H16  = (__half*)alloc((size_t)n * HID * 2);
    __half* H2   = (__half*)alloc((size_t)n * HID * 2);
    __half* Zp   = (__half*)alloc((size_t)n * ZP * 2);

    const int nb = (n + 1023) / 1024;

    k_w1_cvt<<<(FIN * HID) / 256, 256, 0, stream>>>(W1, wt);
    k_w2_cvt<<<(48 * HID) / 256, 256, 0, stream>>>(W2, w2t);

    // CSR: hist + node-level exclusive scan + dinv
    k_zero_int<<<(n + 255) / 256, 256, 0, stream>>>(cnt, n);
    k_hist<<<(E + 255) / 256, 256, 0, stream>>>(dst, E, cnt);
    k_scan1<<<nb, 1024, 0, stream>>>(cnt, off, bsum, n);
    k_scan2<<<1, 64, 0, stream>>>(bsum, nb);
    k_scan3<<<(n + 255) / 256, 256, 0, stream>>>(off, cnt, bsum, dinv, n);

    // two-phase bucket scatter
    k_binit<<<1, 256, 0, stream>>>(off, boff, bcur, n, E, nbk);
    k_bucketize<<<(E + CHUNK - 1) / CHUNK, 256, 0, stream>>>(src, dst, E, bcur, ebkt, nbk);
    k_sortbkt<<<nbk, 512, 0, stream>>>(ebkt, boff, off, dinv, eew, n);

    // layer 1
    k_gemm1<<<(n + 63) / 64, 256, 0, stream>>>(x, wt, H16, n);
    k_agg1<<<(n + 3) / 4, 256, 0, stream>>>(H16, eew, off, cnt, dinv, b1, H2, n);

    // layer 2 + log_softmax
    k_gemm2<<<(n + 63) / 64, 256, 0, stream>>>(H2, w2t, Zp, n);
    k_agg2<<<(n + 3) / 4, 256, 0, stream>>>(Zp, eew, off, cnt, dinv, b2, out, n);
}